// Round 1
// baseline (391.543 us; speedup 1.0000x reference)
//
#include <hip/hip_runtime.h>

// ---------------------------------------------------------------------------
// PerceiverAttentionLayer on MI355X (gfx950)
// B=8, F=4096, Q=64, D=1024, H=16, Dh=64, FL=F+Q=4160, inner=1024
//
// Pipeline:
//   1) ln_kernel   : LN(features)+LN(latents) -> kv_ln (33280x1024 bf16), lat_ln
//   2) wcast_kernel: Wk|Wv -> Wkv_t (2048x1024 bf16, [n][k]); Wq*0.125 -> Wq_t; Wo -> Wo_t
//   3) gemm_tn     : kv_ln @ Wkv_t^T -> KV (33280x2048 bf16)   [dominant, 139.6 GFLOP]
//   4) gemm_tn     : lat_ln @ Wq_t^T -> q_ws (512x1024 bf16, pre-scaled)
//   5) attn_kernel : flash attention per (b,h), online softmax, MFMA 16x16x32
//   6) gemm_tn     : attn_out @ Wo_t^T -> d_out (512x1024 f32)
//
// Workspace requirement: ~206 MiB (see layout in kernel_launch).
// ---------------------------------------------------------------------------

typedef float   f32x4  __attribute__((ext_vector_type(4)));
typedef short   bf16x8 __attribute__((ext_vector_type(8)));

#define MFMA_BF16 __builtin_amdgcn_mfma_f32_16x16x32_bf16

__device__ __forceinline__ unsigned short f2bf(float f) {
  unsigned u = __float_as_uint(f);
  unsigned r = (u + 0x7fffu + ((u >> 16) & 1u)) >> 16;   // RNE
  return (unsigned short)r;
}

__device__ __forceinline__ void gload_lds16(const unsigned short* g, unsigned short* l) {
  // async global->LDS, 16B per lane; LDS dest must be wave-uniform base (lane*16 implicit)
  __builtin_amdgcn_global_load_lds(
      (const __attribute__((address_space(1))) unsigned int*)g,
      (__attribute__((address_space(3))) unsigned int*)l, 16, 0, 0);
}

// ---------------------------------------------------------------------------
// 1) LayerNorm -> bf16.  One block per row (1024 cols, 256 thr x float4).
// rows 0..33279: row = b*4160 + fi; fi<4096 -> features, else latents (also to lat_ln)
// ---------------------------------------------------------------------------
__global__ __launch_bounds__(256) void ln_kernel(
    const float* __restrict__ features, const float* __restrict__ latents,
    const float* __restrict__ lnm_w, const float* __restrict__ lnm_b,
    const float* __restrict__ lnl_w, const float* __restrict__ lnl_b,
    unsigned short* __restrict__ kv_ln, unsigned short* __restrict__ lat_ln)
{
  const int row = blockIdx.x;
  const int b  = row / 4160;
  const int fi = row - b * 4160;
  const bool is_lat = fi >= 4096;
  const float* x = is_lat ? (latents + (size_t)(b * 64 + fi - 4096) * 1024)
                          : (features + (size_t)(b * 4096 + fi) * 1024);
  const float* wp = is_lat ? lnl_w : lnm_w;
  const float* bp = is_lat ? lnl_b : lnm_b;
  const int tid = threadIdx.x;

  float4 v = *(const float4*)(x + tid * 4);
  float s  = v.x + v.y + v.z + v.w;
  float s2 = v.x * v.x + v.y * v.y + v.z * v.z + v.w * v.w;
#pragma unroll
  for (int sh = 1; sh < 64; sh <<= 1) {
    s  += __shfl_xor(s,  sh, 64);
    s2 += __shfl_xor(s2, sh, 64);
  }
  __shared__ float red[8];
  if ((tid & 63) == 0) { red[tid >> 6] = s; red[4 + (tid >> 6)] = s2; }
  __syncthreads();
  s  = red[0] + red[1] + red[2] + red[3];
  s2 = red[4] + red[5] + red[6] + red[7];
  const float mu   = s * (1.0f / 1024.0f);
  const float var  = s2 * (1.0f / 1024.0f) - mu * mu;
  const float rstd = rsqrtf(var + 1e-5f);

  float4 w4 = *(const float4*)(wp + tid * 4);
  float4 b4 = *(const float4*)(bp + tid * 4);
  ushort4 o;
  o.x = f2bf((v.x - mu) * rstd * w4.x + b4.x);
  o.y = f2bf((v.y - mu) * rstd * w4.y + b4.y);
  o.z = f2bf((v.z - mu) * rstd * w4.z + b4.z);
  o.w = f2bf((v.w - mu) * rstd * w4.w + b4.w);
  *(ushort4*)(kv_ln + (size_t)row * 1024 + tid * 4) = o;
  if (is_lat)
    *(ushort4*)(lat_ln + (size_t)(b * 64 + fi - 4096) * 1024 + tid * 4) = o;
}

// ---------------------------------------------------------------------------
// 2) Weight cast + transpose to bf16 [n][k].  Wq gets *0.125 (softmax scale).
// 4M elements total: [0,2M)->Wkv_t, [2M,3M)->Wq_t, [3M,4M)->Wo_t
// ---------------------------------------------------------------------------
__global__ __launch_bounds__(256) void wcast_kernel(
    const float* __restrict__ Wq, const float* __restrict__ Wk,
    const float* __restrict__ Wv, const float* __restrict__ Wo,
    unsigned short* __restrict__ Wkv_t, unsigned short* __restrict__ Wq_t,
    unsigned short* __restrict__ Wo_t)
{
  const unsigned tid = blockIdx.x * 256u + threadIdx.x;
  const unsigned M1 = 1024u * 1024u;
  const unsigned M2 = 2u * M1;
  if (tid < M2) {
    unsigned n = tid >> 10, k = tid & 1023;
    float v = (n < 1024) ? Wk[(size_t)k * 1024 + n] : Wv[(size_t)k * 1024 + (n - 1024)];
    Wkv_t[tid] = f2bf(v);
  } else if (tid < M2 + M1) {
    unsigned t = tid - M2, n = t >> 10, k = t & 1023;
    Wq_t[t] = f2bf(Wq[(size_t)k * 1024 + n] * 0.125f);
  } else {
    unsigned t = tid - M2 - M1, n = t >> 10, k = t & 1023;
    Wo_t[t] = f2bf(Wo[(size_t)k * 1024 + n]);
  }
}

// ---------------------------------------------------------------------------
// 3) GEMM  C(M,N) = A(M,K) @ Bt(N,K)^T   (bf16 in, CT out)
// 128x128 tile, BK=32, 4 waves (each 64x64 = 4x4 frags of 16x16x32 MFMA),
// global_load_lds(16B) double-buffered, 2-phase schedule (m97 structure).
// M%128==0, N%128==0, K%32==0 are guaranteed by the caller.
// ---------------------------------------------------------------------------
template <typename CT>
__global__ __launch_bounds__(256) void gemm_tn(
    const unsigned short* __restrict__ A,
    const unsigned short* __restrict__ Bt,
    CT* __restrict__ C, int M, int N, int K)
{
  __shared__ __align__(16) unsigned short sA[2][128 * 32];
  __shared__ __align__(16) unsigned short sB[2][128 * 32];
  const int tid  = threadIdx.x;
  const int wave = tid >> 6, lane = tid & 63;
  const int bm = blockIdx.y, bn = blockIdx.x;
  const int wr = wave >> 1, wc = wave & 1;
  const int lo = lane & 15, hi = lane >> 4;
  const int srow = lane >> 2, squad = lane & 3;      // staging: 4 lanes/row (16B each)

  const unsigned short* gA = A  + (size_t)(bm * 128 + srow) * K + squad * 8;
  const unsigned short* gB = Bt + (size_t)(bn * 128 + srow) * K + squad * 8;

  f32x4 acc[4][4];
#pragma unroll
  for (int i = 0; i < 4; ++i)
#pragma unroll
    for (int j = 0; j < 4; ++j) acc[i][j] = (f32x4){0.f, 0.f, 0.f, 0.f};

  const int kt = K >> 5;
  // prologue stage -> buf 0
#pragma unroll
  for (int c = 0; c < 2; ++c) {
    const int chunk = wave * 2 + c;                  // 16-row chunk (1024B)
    gload_lds16(gA + (size_t)chunk * 16 * K, &sA[0][chunk * 512]);
    gload_lds16(gB + (size_t)chunk * 16 * K, &sB[0][chunk * 512]);
  }
  __syncthreads();                                   // drains vmcnt

  int buf = 0;
  for (int t = 0; t < kt; ++t) {
    if (t + 1 < kt) {
      const int k0 = (t + 1) << 5;
#pragma unroll
      for (int c = 0; c < 2; ++c) {
        const int chunk = wave * 2 + c;
        gload_lds16(gA + (size_t)chunk * 16 * K + k0, &sA[buf ^ 1][chunk * 512]);
        gload_lds16(gB + (size_t)chunk * 16 * K + k0, &sB[buf ^ 1][chunk * 512]);
      }
    }
    bf16x8 af[4], bfr[4];
#pragma unroll
    for (int i = 0; i < 4; ++i) {
      af[i]  = *(const bf16x8*)&sA[buf][(wr * 64 + i * 16 + lo) * 32 + hi * 8];
      bfr[i] = *(const bf16x8*)&sB[buf][(wc * 64 + i * 16 + lo) * 32 + hi * 8];
    }
#pragma unroll
    for (int i = 0; i < 4; ++i)
#pragma unroll
      for (int j = 0; j < 4; ++j)
        acc[i][j] = MFMA_BF16(af[i], bfr[j], acc[i][j], 0, 0, 0);
    __syncthreads();                                 // drains vmcnt+lgkmcnt for next buf
    buf ^= 1;
  }

  // epilogue: D layout col=lane&15, row=(lane>>4)*4+r  [m89-verified]
#pragma unroll
  for (int i = 0; i < 4; ++i) {
    const int row0 = bm * 128 + wr * 64 + i * 16 + hi * 4;
#pragma unroll
    for (int j = 0; j < 4; ++j) {
      const int col = bn * 128 + wc * 64 + j * 16 + lo;
#pragma unroll
      for (int r = 0; r < 4; ++r) {
        const size_t idx = (size_t)(row0 + r) * N + col;
        if constexpr (sizeof(CT) == 2) C[idx] = (CT)f2bf(acc[i][j][r]);
        else                            C[idx] = acc[i][j][r];
      }
    }
  }
}

// ---------------------------------------------------------------------------
// 5) Flash attention, one WG (4 waves) per (b,h).  Wave w owns queries
// [w*16, w*16+16).  f-loop: 65 tiles of 64.  Q (pre-scaled) in registers.
// sim = mfma(Q, K^T); online softmax in sim layout (q=(hi)*4+r, f=nf*16+lo);
// P -> sP[q][f] (wave-private); out^T = mfma(V^T, P^T) so acc col=q=lo.
// ---------------------------------------------------------------------------
__global__ __launch_bounds__(256) void attn_kernel(
    const unsigned short* __restrict__ qws,      // (512,1024) bf16, pre-scaled
    const unsigned short* __restrict__ KV,       // (33280,2048) bf16: [0:1024)=K, [1024:2048)=V, col h*64+d
    unsigned short* __restrict__ attn_out)       // (512,1024) bf16
{
  const int bh = blockIdx.x;
  const int b = bh >> 4, h = bh & 15;
  const int tid = threadIdx.x;
  const int wave = tid >> 6, lane = tid & 63;
  const int lo = lane & 15, hi = lane >> 4;

  __shared__ __align__(16) unsigned short sK [64][72];   // [f][d], pad 72 (144B rows)
  __shared__ __align__(16) unsigned short sVT[64][72];   // [d][f]
  __shared__ __align__(16) unsigned short sP [4][16][72];// per wave [q][f]

  bf16x8 qf[2];
  {
    const unsigned short* p = qws + (size_t)(b * 64 + wave * 16 + lo) * 1024 + h * 64 + hi * 8;
    qf[0] = *(const bf16x8*)p;
    qf[1] = *(const bf16x8*)(p + 32);
  }
  float m[4] = {-1e30f, -1e30f, -1e30f, -1e30f};
  float l[4] = {0.f, 0.f, 0.f, 0.f};
  f32x4 acc[4];
#pragma unroll
  for (int i = 0; i < 4; ++i) acc[i] = (f32x4){0.f, 0.f, 0.f, 0.f};

  const int frow = tid >> 2, c4 = tid & 3;

  for (int t = 0; t < 65; ++t) {
    __syncthreads();   // prev tile's LDS reads done before overwrite
    {
      const size_t rb = (size_t)(b * 4160 + t * 64 + frow) * 2048 + h * 64;
#pragma unroll
      for (int rr = 0; rr < 2; ++rr) {
        const int d0 = rr * 32 + c4 * 8;
        bf16x8 kvv = *(const bf16x8*)(KV + rb + d0);
        *(bf16x8*)&sK[frow][d0] = kvv;
        bf16x8 vvv = *(const bf16x8*)(KV + rb + 1024 + d0);
#pragma unroll
        for (int j = 0; j < 8; ++j) sVT[d0 + j][frow] = (unsigned short)vvv[j];
      }
    }
    __syncthreads();

    // QK^T: A=Q (rows q), B=K^T (cols f)
    f32x4 sim[4];
#pragma unroll
    for (int nf = 0; nf < 4; ++nf) {
      f32x4 a0 = (f32x4){0.f, 0.f, 0.f, 0.f};
#pragma unroll
      for (int ks = 0; ks < 2; ++ks) {
        bf16x8 kf = *(const bf16x8*)&sK[nf * 16 + lo][ks * 32 + hi * 8];
        a0 = MFMA_BF16(qf[ks], kf, a0, 0, 0, 0);
      }
      sim[nf] = a0;
    }

    // online softmax (row stats across the 16 low lanes)
    float pr[4][4];
    float corr[4];
#pragma unroll
    for (int r = 0; r < 4; ++r) {
      float tm = fmaxf(fmaxf(sim[0][r], sim[1][r]), fmaxf(sim[2][r], sim[3][r]));
#pragma unroll
      for (int sh = 1; sh < 16; sh <<= 1) tm = fmaxf(tm, __shfl_xor(tm, sh, 64));
      const float mn = fmaxf(m[r], tm);
      corr[r] = __expf(m[r] - mn);
      float rs = 0.f;
#pragma unroll
      for (int nf = 0; nf < 4; ++nf) {
        float p = __expf(sim[nf][r] - mn);
        pr[r][nf] = p;
        rs += p;
      }
#pragma unroll
      for (int sh = 1; sh < 16; sh <<= 1) rs += __shfl_xor(rs, sh, 64);
      l[r] = l[r] * corr[r] + rs;
      m[r] = mn;
    }

    // redistribute corr from (hi,r) layout to col-q (=lo) layout
    {
      const int r2 = lane & 3;
      float csel = r2 == 0 ? corr[0] : r2 == 1 ? corr[1] : r2 == 2 ? corr[2] : corr[3];
      const int src = ((lane & 15) >> 2) * 16 + (lane & 3);
      const float cacc = __shfl(csel, src, 64);
#pragma unroll
      for (int i = 0; i < 4; ++i) acc[i] *= cacc;
    }

    // P -> sP (wave-private; within-wave RAW ordered by lgkmcnt)
#pragma unroll
    for (int r = 0; r < 4; ++r)
#pragma unroll
      for (int nf = 0; nf < 4; ++nf)
        sP[wave][hi * 4 + r][nf * 16 + lo] = f2bf(pr[r][nf]);

    // PV: out^T = V^T @ P^T  (A rows = vd, B cols = q)
#pragma unroll
    for (int ks = 0; ks < 2; ++ks) {
      bf16x8 pf = *(const bf16x8*)&sP[wave][lo][ks * 32 + hi * 8];
#pragma unroll
      for (int i = 0; i < 4; ++i) {
        bf16x8 vf = *(const bf16x8*)&sVT[i * 16 + lo][ks * 32 + hi * 8];
        acc[i] = MFMA_BF16(vf, pf, acc[i], 0, 0, 0);
      }
    }
  }

  // finalize: divide by l (redistributed to col-q layout), write out
  const int r2 = lane & 3;
  float lsel = r2 == 0 ? l[0] : r2 == 1 ? l[1] : r2 == 2 ? l[2] : l[3];
  const int src = ((lane & 15) >> 2) * 16 + (lane & 3);
  const float inv = 1.0f / __shfl(lsel, src, 64);
  const size_t orow = (size_t)(b * 64 + wave * 16 + lo) * 1024 + h * 64;
#pragma unroll
  for (int i = 0; i < 4; ++i)
#pragma unroll
    for (int r = 0; r < 4; ++r)
      attn_out[orow + i * 16 + hi * 4 + r] = f2bf(acc[i][r] * inv);
}

// ---------------------------------------------------------------------------
extern "C" void kernel_launch(void* const* d_in, const int* in_sizes, int n_in,
                              void* d_out, int out_size, void* d_ws, size_t ws_size,
                              hipStream_t stream) {
  const float* features = (const float*)d_in[0];
  const float* latents  = (const float*)d_in[1];
  const float* lnm_w = (const float*)d_in[2];
  const float* lnm_b = (const float*)d_in[3];
  const float* lnl_w = (const float*)d_in[4];
  const float* lnl_b = (const float*)d_in[5];
  const float* Wq = (const float*)d_in[6];
  const float* Wk = (const float*)d_in[7];
  const float* Wv = (const float*)d_in[8];
  const float* Wo = (const float*)d_in[9];
  float* out = (float*)d_out;

  // workspace layout (bytes): total 216,006,656 (~206 MiB)
  char* ws = (char*)d_ws;
  unsigned short* kv_ln    = (unsigned short*)(ws);               // 68,157,440 (33280x1024 bf16)
  unsigned short* Wkv_t    = (unsigned short*)(ws + 68157440);    //  4,194,304 (2048x1024)
  unsigned short* Wq_t     = (unsigned short*)(ws + 72351744);    //  2,097,152
  unsigned short* Wo_t     = (unsigned short*)(ws + 74448896);    //  2,097,152
  unsigned short* lat_ln   = (unsigned short*)(ws + 76546048);    //  1,048,576 (512x1024)
  unsigned short* q_ws     = (unsigned short*)(ws + 77594624);    //  1,048,576
  unsigned short* attn_out = (unsigned short*)(ws + 78643200);    //  1,048,576
  unsigned short* KV       = (unsigned short*)(ws + 79691776);    // 136,314,880 (33280x2048)

  ln_kernel<<<33280, 256, 0, stream>>>(features, latents, lnm_w, lnm_b, lnl_w, lnl_b,
                                       kv_ln, lat_ln);
  wcast_kernel<<<16384, 256, 0, stream>>>(Wq, Wk, Wv, Wo, Wkv_t, Wq_t, Wo_t);
  gemm_tn<unsigned short><<<dim3(16, 260), 256, 0, stream>>>(kv_ln, Wkv_t, KV, 33280, 2048, 1024);
  gemm_tn<unsigned short><<<dim3(8, 4), 256, 0, stream>>>(lat_ln, Wq_t, q_ws, 512, 1024, 1024);
  attn_kernel<<<128, 256, 0, stream>>>(q_ws, KV, attn_out);
  gemm_tn<float><<<dim3(8, 4), 256, 0, stream>>>(attn_out, Wo_t, out, 512, 1024, 1024);
}

// Round 3
// 371.790 us; speedup vs baseline: 1.0531x; 1.0531x over previous
//
#include <hip/hip_runtime.h>

// ---------------------------------------------------------------------------
// PerceiverAttentionLayer on MI355X (gfx950)
// B=8, F=4096, Q=64, D=1024, H=16, Dh=64, FL=F+Q=4160, inner=1024
//
// R3 change: fix the last-K-tile race in gemm256_bf16 — epilogue vmcnt drain
// 4->2->0 (R2's vmcnt(6) was a no-op once staging stopped). Rest unchanged.
// ---------------------------------------------------------------------------

typedef float   f32x4  __attribute__((ext_vector_type(4)));
typedef short   bf16x8 __attribute__((ext_vector_type(8)));

#define MFMA_BF16 __builtin_amdgcn_mfma_f32_16x16x32_bf16

__device__ __forceinline__ unsigned short f2bf(float f) {
  unsigned u = __float_as_uint(f);
  unsigned r = (u + 0x7fffu + ((u >> 16) & 1u)) >> 16;   // RNE
  return (unsigned short)r;
}

__device__ __forceinline__ void gload_lds16(const unsigned short* g, unsigned short* l) {
  // async global->LDS, 16B per lane; LDS dest is wave-uniform base (+lane*16 in HW)
  __builtin_amdgcn_global_load_lds(
      (const __attribute__((address_space(1))) unsigned int*)g,
      (__attribute__((address_space(3))) unsigned int*)l, 16, 0, 0);
}

// ---------------------------------------------------------------------------
// 1) LayerNorm -> bf16.  One block per row (1024 cols, 256 thr x float4).
// ---------------------------------------------------------------------------
__global__ __launch_bounds__(256) void ln_kernel(
    const float* __restrict__ features, const float* __restrict__ latents,
    const float* __restrict__ lnm_w, const float* __restrict__ lnm_b,
    const float* __restrict__ lnl_w, const float* __restrict__ lnl_b,
    unsigned short* __restrict__ kv_ln, unsigned short* __restrict__ lat_ln)
{
  const int row = blockIdx.x;
  const int b  = row / 4160;
  const int fi = row - b * 4160;
  const bool is_lat = fi >= 4096;
  const float* x = is_lat ? (latents + (size_t)(b * 64 + fi - 4096) * 1024)
                          : (features + (size_t)(b * 4096 + fi) * 1024);
  const float* wp = is_lat ? lnl_w : lnm_w;
  const float* bp = is_lat ? lnl_b : lnm_b;
  const int tid = threadIdx.x;

  float4 v = *(const float4*)(x + tid * 4);
  float s  = v.x + v.y + v.z + v.w;
  float s2 = v.x * v.x + v.y * v.y + v.z * v.z + v.w * v.w;
#pragma unroll
  for (int sh = 1; sh < 64; sh <<= 1) {
    s  += __shfl_xor(s,  sh, 64);
    s2 += __shfl_xor(s2, sh, 64);
  }
  __shared__ float red[8];
  if ((tid & 63) == 0) { red[tid >> 6] = s; red[4 + (tid >> 6)] = s2; }
  __syncthreads();
  s  = red[0] + red[1] + red[2] + red[3];
  s2 = red[4] + red[5] + red[6] + red[7];
  const float mu   = s * (1.0f / 1024.0f);
  const float var  = s2 * (1.0f / 1024.0f) - mu * mu;
  const float rstd = rsqrtf(var + 1e-5f);

  float4 w4 = *(const float4*)(wp + tid * 4);
  float4 b4 = *(const float4*)(bp + tid * 4);
  ushort4 o;
  o.x = f2bf((v.x - mu) * rstd * w4.x + b4.x);
  o.y = f2bf((v.y - mu) * rstd * w4.y + b4.y);
  o.z = f2bf((v.z - mu) * rstd * w4.z + b4.z);
  o.w = f2bf((v.w - mu) * rstd * w4.w + b4.w);
  *(ushort4*)(kv_ln + (size_t)row * 1024 + tid * 4) = o;
  if (is_lat)
    *(ushort4*)(lat_ln + (size_t)(b * 64 + fi - 4096) * 1024 + tid * 4) = o;
}

// ---------------------------------------------------------------------------
// 2) Weight cast + transpose to bf16 [n][k].  Wq gets *0.125 (softmax scale).
// ---------------------------------------------------------------------------
__global__ __launch_bounds__(256) void wcast_kernel(
    const float* __restrict__ Wq, const float* __restrict__ Wk,
    const float* __restrict__ Wv, const float* __restrict__ Wo,
    unsigned short* __restrict__ Wkv_t, unsigned short* __restrict__ Wq_t,
    unsigned short* __restrict__ Wo_t)
{
  const unsigned tid = blockIdx.x * 256u + threadIdx.x;
  const unsigned M1 = 1024u * 1024u;
  const unsigned M2 = 2u * M1;
  if (tid < M2) {
    unsigned n = tid >> 10, k = tid & 1023;
    float v = (n < 1024) ? Wk[(size_t)k * 1024 + n] : Wv[(size_t)k * 1024 + (n - 1024)];
    Wkv_t[tid] = f2bf(v);
  } else if (tid < M2 + M1) {
    unsigned t = tid - M2, n = t >> 10, k = t & 1023;
    Wq_t[t] = f2bf(Wq[(size_t)k * 1024 + n] * 0.125f);
  } else {
    unsigned t = tid - M2 - M1, n = t >> 10, k = t & 1023;
    Wo_t[t] = f2bf(Wo[(size_t)k * 1024 + n]);
  }
}

// ---------------------------------------------------------------------------
// 3a) 256^2 8-phase GEMM  C(M,N) = A(M,K) @ Bt(N,K)^T  (bf16 in, bf16 out)
// 512 threads (8 waves).  LDS: 8 half-tile slots x 16KB (2-tile dbuf),
// st_16x32 swizzle on read addr, inverse-applied on the global source.
// Steady state: stage 1 half-tile/phase, vmcnt(6) publishes the next slot.
// Last tile (no staging): drain vmcnt 4 -> 2 -> 0 across phases 0..2.
// Requires M%256==0, N%256==0, K%64==0.
// ---------------------------------------------------------------------------
__global__ __launch_bounds__(512, 2) void gemm256_bf16(
    const unsigned short* __restrict__ A,
    const unsigned short* __restrict__ Bt,
    unsigned short* __restrict__ C, int M, int N, int K)
{
  __shared__ __align__(16) unsigned short lds[65536];   // 128 KiB
  const int tid  = threadIdx.x;
  const int wave = tid >> 6, lane = tid & 63;
  const int lo = lane & 15, hi = lane >> 4;
  const int wr = wave >> 2, wc = wave & 3;
  const int bm = blockIdx.y, bn = blockIdx.x;

  // staging map: thread t covers LDS bytes [16t,16t+16) of a half-tile slot;
  // logical element offset = swz(16t) -> (row, col) in the [128][64] half-tile
  int roff[2], coff[2];
#pragma unroll
  for (int g = 0; g < 2; ++g) {
    int off = g * 8192 + tid * 16;
    int p = off ^ (((off >> 9) & 1) << 5);
    int sub = (p >> 10) & 15;
    int q = p & 1023;
    roff[g] = ((sub >> 1) << 4) + (q >> 6);
    coff[g] = ((sub & 1) << 5) + ((q & 63) >> 1);
  }
  const unsigned short* pA[2];
  const unsigned short* pB[2];
#pragma unroll
  for (int g = 0; g < 2; ++g) {
    pA[g] = A  + (size_t)(bm * 256 + roff[g]) * K + coff[g];
    pB[g] = Bt + (size_t)(bn * 256 + roff[g]) * K + coff[g];
  }
  const int halfStep = 128 * K;   // +128 rows

  f32x4 acc[8][4];
#pragma unroll
  for (int i = 0; i < 8; ++i)
#pragma unroll
    for (int j = 0; j < 4; ++j) acc[i][j] = (f32x4){0.f, 0.f, 0.f, 0.f};

  const int NT = K >> 6;          // K-tiles of 64

  // prologue: stage tile 0 (slots 0..3: A-h0, B-h0, A-h1, B-h1)
#pragma unroll
  for (int ty = 0; ty < 4; ++ty) {
#pragma unroll
    for (int g = 0; g < 2; ++g) {
      const unsigned short* src = (ty == 0) ? pA[g]
                                : (ty == 1) ? pB[g]
                                : (ty == 2) ? pA[g] + halfStep
                                            : pB[g] + halfStep;
      gload_lds16(src, lds + ty * 8192 + g * 4096 + wave * 512);
    }
  }
  asm volatile("s_waitcnt vmcnt(6)" ::: "memory");   // slot 0 landed
  asm volatile("s_barrier" ::: "memory");

  bf16x8 aLo[4][2], aHi[4][2], bLo[2][2], bHi[2][2];
  const int swz = (lo * 32 + hi * 8) ^ ((lo & 8) << 1);   // ushort units

#pragma unroll 2
  for (int t = 0; t < NT; ++t) {
    const unsigned short* sb = lds + (t & 1) * 32768;
    unsigned short*       db = lds + ((t + 1) & 1) * 32768;
    const int k0n = (t + 1) << 6;
    const bool st = (t + 1 < NT);

    // ---- phase 0: read A-h0 frags; stage next A-h0; MFMA leftover (m4-7,n2-3)
#pragma unroll
    for (int m = 0; m < 4; ++m)
#pragma unroll
      for (int ks = 0; ks < 2; ++ks)
        aLo[m][ks] = *(const bf16x8*)(sb + ((wr * 4 + m) * 2 + ks) * 512 + swz);
    if (st) {
#pragma unroll
      for (int g = 0; g < 2; ++g)
        gload_lds16(pA[g] + k0n, db + g * 4096 + wave * 512);
    }
    asm volatile("s_barrier" ::: "memory");
    asm volatile("s_waitcnt lgkmcnt(0)" ::: "memory");
    __builtin_amdgcn_sched_barrier(0);
    __builtin_amdgcn_s_setprio(1);
    if (t > 0) {
#pragma unroll
      for (int m = 0; m < 4; ++m)
#pragma unroll
        for (int n = 0; n < 2; ++n)
#pragma unroll
          for (int ks = 0; ks < 2; ++ks)
            acc[4 + m][2 + n] = MFMA_BF16(aHi[m][ks], bHi[n][ks], acc[4 + m][2 + n], 0, 0, 0);
    }
    __builtin_amdgcn_s_setprio(0);
    if (st) { asm volatile("s_waitcnt vmcnt(6)" ::: "memory"); }
    else    { asm volatile("s_waitcnt vmcnt(4)" ::: "memory"); }  // B-h0 landed
    asm volatile("s_barrier" ::: "memory");

    // ---- phase 1: read B-h0 frags; stage next B-h0; MFMA (m0-3, n0-1)
#pragma unroll
    for (int n = 0; n < 2; ++n)
#pragma unroll
      for (int ks = 0; ks < 2; ++ks)
        bLo[n][ks] = *(const bf16x8*)(sb + 8192 + ((wc * 2 + n) * 2 + ks) * 512 + swz);
    if (st) {
#pragma unroll
      for (int g = 0; g < 2; ++g)
        gload_lds16(pB[g] + k0n, db + 8192 + g * 4096 + wave * 512);
    }
    asm volatile("s_barrier" ::: "memory");
    asm volatile("s_waitcnt lgkmcnt(0)" ::: "memory");
    __builtin_amdgcn_sched_barrier(0);
    __builtin_amdgcn_s_setprio(1);
#pragma unroll
    for (int m = 0; m < 4; ++m)
#pragma unroll
      for (int n = 0; n < 2; ++n)
#pragma unroll
        for (int ks = 0; ks < 2; ++ks)
          acc[m][n] = MFMA_BF16(aLo[m][ks], bLo[n][ks], acc[m][n], 0, 0, 0);
    __builtin_amdgcn_s_setprio(0);
    if (st) { asm volatile("s_waitcnt vmcnt(6)" ::: "memory"); }
    else    { asm volatile("s_waitcnt vmcnt(2)" ::: "memory"); }  // A-h1 landed
    asm volatile("s_barrier" ::: "memory");

    // ---- phase 2: read A-h1 frags; stage next A-h1; MFMA (m4-7, n0-1)
#pragma unroll
    for (int m = 0; m < 4; ++m)
#pragma unroll
      for (int ks = 0; ks < 2; ++ks)
        aHi[m][ks] = *(const bf16x8*)(sb + 16384 + ((wr * 4 + m) * 2 + ks) * 512 + swz);
    if (st) {
#pragma unroll
      for (int g = 0; g < 2; ++g)
        gload_lds16(pA[g] + halfStep + k0n, db + 16384 + g * 4096 + wave * 512);
    }
    asm volatile("s_barrier" ::: "memory");
    asm volatile("s_waitcnt lgkmcnt(0)" ::: "memory");
    __builtin_amdgcn_sched_barrier(0);
    __builtin_amdgcn_s_setprio(1);
#pragma unroll
    for (int m = 0; m < 4; ++m)
#pragma unroll
      for (int n = 0; n < 2; ++n)
#pragma unroll
        for (int ks = 0; ks < 2; ++ks)
          acc[4 + m][n] = MFMA_BF16(aHi[m][ks], bLo[n][ks], acc[4 + m][n], 0, 0, 0);
    __builtin_amdgcn_s_setprio(0);
    if (st) { asm volatile("s_waitcnt vmcnt(6)" ::: "memory"); }
    else    { asm volatile("s_waitcnt vmcnt(0)" ::: "memory"); }  // B-h1 landed
    asm volatile("s_barrier" ::: "memory");

    // ---- phase 3: read B-h1 frags; stage next B-h1; MFMA (m0-3, n2-3)
#pragma unroll
    for (int n = 0; n < 2; ++n)
#pragma unroll
      for (int ks = 0; ks < 2; ++ks)
        bHi[n][ks] = *(const bf16x8*)(sb + 24576 + ((wc * 2 + n) * 2 + ks) * 512 + swz);
    if (st) {
#pragma unroll
      for (int g = 0; g < 2; ++g)
        gload_lds16(pB[g] + halfStep + k0n, db + 24576 + g * 4096 + wave * 512);
    }
    asm volatile("s_barrier" ::: "memory");
    asm volatile("s_waitcnt lgkmcnt(0)" ::: "memory");
    __builtin_amdgcn_sched_barrier(0);
    __builtin_amdgcn_s_setprio(1);
#pragma unroll
    for (int m = 0; m < 4; ++m)
#pragma unroll
      for (int n = 0; n < 2; ++n)
#pragma unroll
        for (int ks = 0; ks < 2; ++ks)
          acc[m][2 + n] = MFMA_BF16(aLo[m][ks], bHi[n][ks], acc[m][2 + n], 0, 0, 0);
    __builtin_amdgcn_s_setprio(0);
    if (st) { asm volatile("s_waitcnt vmcnt(6)" ::: "memory"); }  // next A-h0 landed
    asm volatile("s_barrier" ::: "memory");
  }

  // final leftover quadrant of the last tile
#pragma unroll
  for (int m = 0; m < 4; ++m)
#pragma unroll
    for (int n = 0; n < 2; ++n)
#pragma unroll
      for (int ks = 0; ks < 2; ++ks)
        acc[4 + m][2 + n] = MFMA_BF16(aHi[m][ks], bHi[n][ks], acc[4 + m][2 + n], 0, 0, 0);

  // epilogue: D layout col=lane&15, row=(lane>>4)*4+r
#pragma unroll
  for (int i = 0; i < 8; ++i) {
    const int grow0 = bm * 256 + (i >> 2) * 128 + wr * 64 + (i & 3) * 16 + hi * 4;
#pragma unroll
    for (int j = 0; j < 4; ++j) {
      const int gcol = bn * 256 + (j >> 1) * 128 + wc * 32 + (j & 1) * 16 + lo;
#pragma unroll
      for (int r = 0; r < 4; ++r)
        C[(size_t)(grow0 + r) * N + gcol] = f2bf(acc[i][j][r]);
    }
  }
}

// ---------------------------------------------------------------------------
// 3b) 128^2 2-phase GEMM for the small projections (M=512).
// ---------------------------------------------------------------------------
template <typename CT>
__global__ __launch_bounds__(256) void gemm_tn(
    const unsigned short* __restrict__ A,
    const unsigned short* __restrict__ Bt,
    CT* __restrict__ C, int M, int N, int K)
{
  __shared__ __align__(16) unsigned short sA[2][128 * 32];
  __shared__ __align__(16) unsigned short sB[2][128 * 32];
  const int tid  = threadIdx.x;
  const int wave = tid >> 6, lane = tid & 63;
  const int bm = blockIdx.y, bn = blockIdx.x;
  const int wr = wave >> 1, wc = wave & 1;
  const int lo = lane & 15, hi = lane >> 4;
  const int srow = lane >> 2, squad = lane & 3;

  const unsigned short* gA = A  + (size_t)(bm * 128 + srow) * K + squad * 8;
  const unsigned short* gB = Bt + (size_t)(bn * 128 + srow) * K + squad * 8;

  f32x4 acc[4][4];
#pragma unroll
  for (int i = 0; i < 4; ++i)
#pragma unroll
    for (int j = 0; j < 4; ++j) acc[i][j] = (f32x4){0.f, 0.f, 0.f, 0.f};

  const int kt = K >> 5;
#pragma unroll
  for (int c = 0; c < 2; ++c) {
    const int chunk = wave * 2 + c;
    gload_lds16(gA + (size_t)chunk * 16 * K, &sA[0][chunk * 512]);
    gload_lds16(gB + (size_t)chunk * 16 * K, &sB[0][chunk * 512]);
  }
  __syncthreads();

  int buf = 0;
  for (int t = 0; t < kt; ++t) {
    if (t + 1 < kt) {
      const int k0 = (t + 1) << 5;
#pragma unroll
      for (int c = 0; c < 2; ++c) {
        const int chunk = wave * 2 + c;
        gload_lds16(gA + (size_t)chunk * 16 * K + k0, &sA[buf ^ 1][chunk * 512]);
        gload_lds16(gB + (size_t)chunk * 16 * K + k0, &sB[buf ^ 1][chunk * 512]);
      }
    }
    bf16x8 af[4], bfr[4];
#pragma unroll
    for (int i = 0; i < 4; ++i) {
      af[i]  = *(const bf16x8*)&sA[buf][(wr * 64 + i * 16 + lo) * 32 + hi * 8];
      bfr[i] = *(const bf16x8*)&sB[buf][(wc * 64 + i * 16 + lo) * 32 + hi * 8];
    }
#pragma unroll
    for (int i = 0; i < 4; ++i)
#pragma unroll
      for (int j = 0; j < 4; ++j)
        acc[i][j] = MFMA_BF16(af[i], bfr[j], acc[i][j], 0, 0, 0);
    __syncthreads();
    buf ^= 1;
  }

#pragma unroll
  for (int i = 0; i < 4; ++i) {
    const int row0 = bm * 128 + wr * 64 + i * 16 + hi * 4;
#pragma unroll
    for (int j = 0; j < 4; ++j) {
      const int col = bn * 128 + wc * 64 + j * 16 + lo;
#pragma unroll
      for (int r = 0; r < 4; ++r) {
        const size_t idx = (size_t)(row0 + r) * N + col;
        if constexpr (sizeof(CT) == 2) C[idx] = (CT)f2bf(acc[i][j][r]);
        else                            C[idx] = acc[i][j][r];
      }
    }
  }
}

// ---------------------------------------------------------------------------
// 5) Flash attention, one WG (4 waves) per (b,h).
// ---------------------------------------------------------------------------
__global__ __launch_bounds__(256) void attn_kernel(
    const unsigned short* __restrict__ qws,      // (512,1024) bf16, pre-scaled
    const unsigned short* __restrict__ KV,       // (33280,2048) bf16
    unsigned short* __restrict__ attn_out)       // (512,1024) bf16
{
  const int bh = blockIdx.x;
  const int b = bh >> 4, h = bh & 15;
  const int tid = threadIdx.x;
  const int wave = tid >> 6, lane = tid & 63;
  const int lo = lane & 15, hi = lane >> 4;

  __shared__ __align__(16) unsigned short sK [64][72];
  __shared__ __align__(16) unsigned short sVT[64][72];
  __shared__ __align__(16) unsigned short sP [4][16][72];

  bf16x8 qf[2];
  {
    const unsigned short* p = qws + (size_t)(b * 64 + wave * 16 + lo) * 1024 + h * 64 + hi * 8;
    qf[0] = *(const bf16x8*)p;
    qf[1] = *(const bf16x8*)(p + 32);
  }
  float m[4] = {-1e30f, -1e30f, -1e30f, -1e30f};
  float l[4] = {0.f, 0.f, 0.f, 0.f};
  f32x4 acc[4];
#pragma unroll
  for (int i = 0; i < 4; ++i) acc[i] = (f32x4){0.f, 0.f, 0.f, 0.f};

  const int frow = tid >> 2, c4 = tid & 3;

  for (int t = 0; t < 65; ++t) {
    __syncthreads();
    {
      const size_t rb = (size_t)(b * 4160 + t * 64 + frow) * 2048 + h * 64;
#pragma unroll
      for (int rr = 0; rr < 2; ++rr) {
        const int d0 = rr * 32 + c4 * 8;
        bf16x8 kvv = *(const bf16x8*)(KV + rb + d0);
        *(bf16x8*)&sK[frow][d0] = kvv;
        bf16x8 vvv = *(const bf16x8*)(KV + rb + 1024 + d0);
#pragma unroll
        for (int j = 0; j < 8; ++j) sVT[d0 + j][frow] = (unsigned short)vvv[j];
      }
    }
    __syncthreads();

    f32x4 sim[4];
#pragma unroll
    for (int nf = 0; nf < 4; ++nf) {
      f32x4 a0 = (f32x4){0.f, 0.f, 0.f, 0.f};
#pragma unroll
      for (int ks = 0; ks < 2; ++ks) {
        bf16x8 kf = *(const bf16x8*)&sK[nf * 16 + lo][ks * 32 + hi * 8];
        a0 = MFMA_BF16(qf[ks], kf, a0, 0, 0, 0);
      }
      sim[nf] = a0;
    }

    float pr[4][4];
    float corr[4];
#pragma unroll
    for (int r = 0; r < 4; ++r) {
      float tm = fmaxf(fmaxf(sim[0][r], sim[1][r]), fmaxf(sim[2][r], sim[3][r]));
#pragma unroll
      for (int sh = 1; sh < 16; sh <<= 1) tm = fmaxf(tm, __shfl_xor(tm, sh, 64));
      const float mn = fmaxf(m[r], tm);
      corr[r] = __expf(m[r] - mn);
      float rs = 0.f;
#pragma unroll
      for (int nf = 0; nf < 4; ++nf) {
        float p = __expf(sim[nf][r] - mn);
        pr[r][nf] = p;
        rs += p;
      }
#pragma unroll
      for (int sh = 1; sh < 16; sh <<= 1) rs += __shfl_xor(rs, sh, 64);
      l[r] = l[r] * corr[r] + rs;
      m[r] = mn;
    }

    {
      const int r2 = lane & 3;
      float csel = r2 == 0 ? corr[0] : r2 == 1 ? corr[1] : r2 == 2 ? corr[2] : corr[3];
      const int src = ((lane & 15) >> 2) * 16 + (lane & 3);
      const float cacc = __shfl(csel, src, 64);
#pragma unroll
      for (int i = 0; i < 4; ++i) acc[i] *= cacc;
    }

#pragma unroll
    for (int r = 0; r < 4; ++r)
#pragma unroll
      for (int nf = 0; nf < 4; ++nf)
        sP[wave][hi * 4 + r][nf * 16 + lo] = f2bf(pr[r][nf]);

#pragma unroll
    for (int ks = 0; ks < 2; ++ks) {
      bf16x8 pf = *(const bf16x8*)&sP[wave][lo][ks * 32 + hi * 8];
#pragma unroll
      for (int i = 0; i < 4; ++i) {
        bf16x8 vf = *(const bf16x8*)&sVT[i * 16 + lo][ks * 32 + hi * 8];
        acc[i] = MFMA_BF16(vf, pf, acc[i], 0, 0, 0);
      }
    }
  }

  const int r2 = lane & 3;
  float lsel = r2 == 0 ? l[0] : r2 == 1 ? l[1] : r2 == 2 ? l[2] : l[3];
  const int src = ((lane & 15) >> 2) * 16 + (lane & 3);
  const float inv = 1.0f / __shfl(lsel, src, 64);
  const size_t orow = (size_t)(b * 64 + wave * 16 + lo) * 1024 + h * 64;
#pragma unroll
  for (int i = 0; i < 4; ++i)
#pragma unroll
    for (int r = 0; r < 4; ++r)
      attn_out[orow + i * 16 + hi * 4 + r] = f2bf(acc[i][r] * inv);
}

// ---------------------------------------------------------------------------
extern "C" void kernel_launch(void* const* d_in, const int* in_sizes, int n_in,
                              void* d_out, int out_size, void* d_ws, size_t ws_size,
                              hipStream_t stream) {
  const float* features = (const float*)d_in[0];
  const float* latents  = (const float*)d_in[1];
  const float* lnm_w = (const float*)d_in[2];
  const float* lnm_b = (const float*)d_in[3];
  const float* lnl_w = (const float*)d_in[4];
  const float* lnl_b = (const float*)d_in[5];
  const float* Wq = (const float*)d_in[6];
  const float* Wk = (const float*)d_in[7];
  const float* Wv = (const float*)d_in[8];
  const float* Wo = (const float*)d_in[9];
  float* out = (float*)d_out;

  char* ws = (char*)d_ws;
  unsigned short* kv_ln    = (unsigned short*)(ws);               // 68,157,440
  unsigned short* Wkv_t    = (unsigned short*)(ws + 68157440);    //  4,194,304
  unsigned short* Wq_t     = (unsigned short*)(ws + 72351744);    //  2,097,152
  unsigned short* Wo_t     = (unsigned short*)(ws + 74448896);    //  2,097,152
  unsigned short* lat_ln   = (unsigned short*)(ws + 76546048);    //  1,048,576
  unsigned short* q_ws     = (unsigned short*)(ws + 77594624);    //  1,048,576
  unsigned short* attn_out = (unsigned short*)(ws + 78643200);    //  1,048,576
  unsigned short* KV       = (unsigned short*)(ws + 79691776);    // 136,314,880

  ln_kernel<<<33280, 256, 0, stream>>>(features, latents, lnm_w, lnm_b, lnl_w, lnl_b,
                                       kv_ln, lat_ln);
  wcast_kernel<<<16384, 256, 0, stream>>>(Wq, Wk, Wv, Wo, Wkv_t, Wq_t, Wo_t);
  gemm256_bf16<<<dim3(8, 130), 512, 0, stream>>>(kv_ln, Wkv_t, KV, 33280, 2048, 1024);
  gemm_tn<unsigned short><<<dim3(8, 4), 256, 0, stream>>>(lat_ln, Wq_t, q_ws, 512, 1024, 1024);
  attn_kernel<<<128, 256, 0, stream>>>(q_ws, KV, attn_out);
  gemm_tn<float><<<dim3(8, 4), 256, 0, stream>>>(attn_out, Wo_t, out, 512, 1024, 1024);
}

// Round 4
// 292.948 us; speedup vs baseline: 1.3366x; 1.2691x over previous
//
#include <hip/hip_runtime.h>

// ---------------------------------------------------------------------------
// PerceiverAttentionLayer on MI355X (gfx950)
// B=8, F=4096, Q=64, D=1024, H=16, Dh=64, FL=F+Q=4160, inner=1024
//
// R4 changes:
//  - gemm256: T1 XCD-aware bijective blockIdx swizzle (1040 WGs % 8 == 0)
//  - wcast: 32x32 LDS-tile transpose (was stride-4KB scalar reads)
//  - attn: 4-way f-split (512 WGs, 2 WG/CU), reg-prefetch of next K/V tile,
//          unnormalized partials (acc,m,l) + combine kernel. Partials reuse
//          the kv_ln region (dead after the KV GEMM).
// ---------------------------------------------------------------------------

typedef float   f32x4  __attribute__((ext_vector_type(4)));
typedef short   bf16x8 __attribute__((ext_vector_type(8)));

#define MFMA_BF16 __builtin_amdgcn_mfma_f32_16x16x32_bf16

__device__ __forceinline__ unsigned short f2bf(float f) {
  unsigned u = __float_as_uint(f);
  unsigned r = (u + 0x7fffu + ((u >> 16) & 1u)) >> 16;   // RNE
  return (unsigned short)r;
}

__device__ __forceinline__ void gload_lds16(const unsigned short* g, unsigned short* l) {
  // async global->LDS, 16B per lane; LDS dest is wave-uniform base (+lane*16 in HW)
  __builtin_amdgcn_global_load_lds(
      (const __attribute__((address_space(1))) unsigned int*)g,
      (__attribute__((address_space(3))) unsigned int*)l, 16, 0, 0);
}

// ---------------------------------------------------------------------------
// 1) LayerNorm -> bf16.  One block per row (1024 cols, 256 thr x float4).
// ---------------------------------------------------------------------------
__global__ __launch_bounds__(256) void ln_kernel(
    const float* __restrict__ features, const float* __restrict__ latents,
    const float* __restrict__ lnm_w, const float* __restrict__ lnm_b,
    const float* __restrict__ lnl_w, const float* __restrict__ lnl_b,
    unsigned short* __restrict__ kv_ln, unsigned short* __restrict__ lat_ln)
{
  const int row = blockIdx.x;
  const int b  = row / 4160;
  const int fi = row - b * 4160;
  const bool is_lat = fi >= 4096;
  const float* x = is_lat ? (latents + (size_t)(b * 64 + fi - 4096) * 1024)
                          : (features + (size_t)(b * 4096 + fi) * 1024);
  const float* wp = is_lat ? lnl_w : lnm_w;
  const float* bp = is_lat ? lnl_b : lnm_b;
  const int tid = threadIdx.x;

  float4 v = *(const float4*)(x + tid * 4);
  float s  = v.x + v.y + v.z + v.w;
  float s2 = v.x * v.x + v.y * v.y + v.z * v.z + v.w * v.w;
#pragma unroll
  for (int sh = 1; sh < 64; sh <<= 1) {
    s  += __shfl_xor(s,  sh, 64);
    s2 += __shfl_xor(s2, sh, 64);
  }
  __shared__ float red[8];
  if ((tid & 63) == 0) { red[tid >> 6] = s; red[4 + (tid >> 6)] = s2; }
  __syncthreads();
  s  = red[0] + red[1] + red[2] + red[3];
  s2 = red[4] + red[5] + red[6] + red[7];
  const float mu   = s * (1.0f / 1024.0f);
  const float var  = s2 * (1.0f / 1024.0f) - mu * mu;
  const float rstd = rsqrtf(var + 1e-5f);

  float4 w4 = *(const float4*)(wp + tid * 4);
  float4 b4 = *(const float4*)(bp + tid * 4);
  ushort4 o;
  o.x = f2bf((v.x - mu) * rstd * w4.x + b4.x);
  o.y = f2bf((v.y - mu) * rstd * w4.y + b4.y);
  o.z = f2bf((v.z - mu) * rstd * w4.z + b4.z);
  o.w = f2bf((v.w - mu) * rstd * w4.w + b4.w);
  *(ushort4*)(kv_ln + (size_t)row * 1024 + tid * 4) = o;
  if (is_lat)
    *(ushort4*)(lat_ln + (size_t)(b * 64 + fi - 4096) * 1024 + tid * 4) = o;
}

// ---------------------------------------------------------------------------
// 2) Weight cast+transpose via 32x32 LDS tiles (coalesced read AND write).
// n-space: [0,2048)=Wkv_t (Wk|Wv), [2048,3072)=Wq_t (*0.125), [3072,4096)=Wo_t
// grid (32 k-tiles, 128 n-tiles), 256 threads.
// ---------------------------------------------------------------------------
__global__ __launch_bounds__(256) void wcast_kernel(
    const float* __restrict__ Wq, const float* __restrict__ Wk,
    const float* __restrict__ Wv, const float* __restrict__ Wo,
    unsigned short* __restrict__ Wkv_t, unsigned short* __restrict__ Wq_t,
    unsigned short* __restrict__ Wo_t)
{
  __shared__ float tile[32][33];
  const int kt = blockIdx.x * 32, nt = blockIdx.y * 32;
  const int tx = threadIdx.x & 31, ty = threadIdx.x >> 5;

  const float* src; int nc; float scale = 1.0f;       // uniform per block
  if (nt < 1024)      { src = Wk; nc = nt; }
  else if (nt < 2048) { src = Wv; nc = nt - 1024; }
  else if (nt < 3072) { src = Wq; nc = nt - 2048; scale = 0.125f; }
  else                { src = Wo; nc = nt - 3072; }

#pragma unroll
  for (int kk = 0; kk < 4; ++kk)
    tile[ty + kk * 8][tx] = src[(size_t)(kt + ty + kk * 8) * 1024 + nc + tx] * scale;
  __syncthreads();

#pragma unroll
  for (int nn = 0; nn < 4; ++nn) {
    const int ng = nt + ty + nn * 8;
    unsigned short* d;
    if (ng < 2048)      d = Wkv_t + (size_t)ng * 1024;
    else if (ng < 3072) d = Wq_t + (size_t)(ng - 2048) * 1024;
    else                d = Wo_t + (size_t)(ng - 3072) * 1024;
    d[kt + tx] = f2bf(tile[tx][ty + nn * 8]);
  }
}

// ---------------------------------------------------------------------------
// 3a) 256^2 8-phase GEMM  C(M,N) = A(M,K) @ Bt(N,K)^T  (bf16 in, bf16 out)
// + T1 XCD-aware bijective swizzle (requires total WGs % 8 == 0).
// Steady state: stage 1 half-tile/phase, vmcnt(6); last tile drains 4->2->0.
// ---------------------------------------------------------------------------
__global__ __launch_bounds__(512, 2) void gemm256_bf16(
    const unsigned short* __restrict__ A,
    const unsigned short* __restrict__ Bt,
    unsigned short* __restrict__ C, int M, int N, int K)
{
  __shared__ __align__(16) unsigned short lds[65536];   // 128 KiB
  const int tid  = threadIdx.x;
  const int wave = tid >> 6, lane = tid & 63;
  const int lo = lane & 15, hi = lane >> 4;
  const int wr = wave >> 2, wc = wave & 3;

  // T1: XCD-chunked bijective remap (nwg % 8 == 0 guaranteed by caller)
  const int nbn = gridDim.x;
  int flat = blockIdx.y * nbn + blockIdx.x;
  const int nwg = nbn * gridDim.y;
  flat = (flat & 7) * (nwg >> 3) + (flat >> 3);
  const int bm = flat / nbn, bn = flat - bm * nbn;

  // staging map: thread t covers LDS bytes [16t,16t+16) of a half-tile slot;
  // logical element offset = swz(16t) -> (row, col) in the [128][64] half-tile
  int roff[2], coff[2];
#pragma unroll
  for (int g = 0; g < 2; ++g) {
    int off = g * 8192 + tid * 16;
    int p = off ^ (((off >> 9) & 1) << 5);
    int sub = (p >> 10) & 15;
    int q = p & 1023;
    roff[g] = ((sub >> 1) << 4) + (q >> 6);
    coff[g] = ((sub & 1) << 5) + ((q & 63) >> 1);
  }
  const unsigned short* pA[2];
  const unsigned short* pB[2];
#pragma unroll
  for (int g = 0; g < 2; ++g) {
    pA[g] = A  + (size_t)(bm * 256 + roff[g]) * K + coff[g];
    pB[g] = Bt + (size_t)(bn * 256 + roff[g]) * K + coff[g];
  }
  const int halfStep = 128 * K;   // +128 rows

  f32x4 acc[8][4];
#pragma unroll
  for (int i = 0; i < 8; ++i)
#pragma unroll
    for (int j = 0; j < 4; ++j) acc[i][j] = (f32x4){0.f, 0.f, 0.f, 0.f};

  const int NT = K >> 6;          // K-tiles of 64

  // prologue: stage tile 0 (slots 0..3: A-h0, B-h0, A-h1, B-h1)
#pragma unroll
  for (int ty = 0; ty < 4; ++ty) {
#pragma unroll
    for (int g = 0; g < 2; ++g) {
      const unsigned short* src = (ty == 0) ? pA[g]
                                : (ty == 1) ? pB[g]
                                : (ty == 2) ? pA[g] + halfStep
                                            : pB[g] + halfStep;
      gload_lds16(src, lds + ty * 8192 + g * 4096 + wave * 512);
    }
  }
  asm volatile("s_waitcnt vmcnt(6)" ::: "memory");   // slot 0 landed
  asm volatile("s_barrier" ::: "memory");

  bf16x8 aLo[4][2], aHi[4][2], bLo[2][2], bHi[2][2];
  const int swz = (lo * 32 + hi * 8) ^ ((lo & 8) << 1);   // ushort units

#pragma unroll 2
  for (int t = 0; t < NT; ++t) {
    const unsigned short* sb = lds + (t & 1) * 32768;
    unsigned short*       db = lds + ((t + 1) & 1) * 32768;
    const int k0n = (t + 1) << 6;
    const bool st = (t + 1 < NT);

    // ---- phase 0: read A-h0 frags; stage next A-h0; MFMA leftover (m4-7,n2-3)
#pragma unroll
    for (int m = 0; m < 4; ++m)
#pragma unroll
      for (int ks = 0; ks < 2; ++ks)
        aLo[m][ks] = *(const bf16x8*)(sb + ((wr * 4 + m) * 2 + ks) * 512 + swz);
    if (st) {
#pragma unroll
      for (int g = 0; g < 2; ++g)
        gload_lds16(pA[g] + k0n, db + g * 4096 + wave * 512);
    }
    asm volatile("s_barrier" ::: "memory");
    asm volatile("s_waitcnt lgkmcnt(0)" ::: "memory");
    __builtin_amdgcn_sched_barrier(0);
    __builtin_amdgcn_s_setprio(1);
    if (t > 0) {
#pragma unroll
      for (int m = 0; m < 4; ++m)
#pragma unroll
        for (int n = 0; n < 2; ++n)
#pragma unroll
          for (int ks = 0; ks < 2; ++ks)
            acc[4 + m][2 + n] = MFMA_BF16(aHi[m][ks], bHi[n][ks], acc[4 + m][2 + n], 0, 0, 0);
    }
    __builtin_amdgcn_s_setprio(0);
    if (st) { asm volatile("s_waitcnt vmcnt(6)" ::: "memory"); }
    else    { asm volatile("s_waitcnt vmcnt(4)" ::: "memory"); }  // B-h0 landed
    asm volatile("s_barrier" ::: "memory");

    // ---- phase 1: read B-h0 frags; stage next B-h0; MFMA (m0-3, n0-1)
#pragma unroll
    for (int n = 0; n < 2; ++n)
#pragma unroll
      for (int ks = 0; ks < 2; ++ks)
        bLo[n][ks] = *(const bf16x8*)(sb + 8192 + ((wc * 2 + n) * 2 + ks) * 512 + swz);
    if (st) {
#pragma unroll
      for (int g = 0; g < 2; ++g)
        gload_lds16(pB[g] + k0n, db + 8192 + g * 4096 + wave * 512);
    }
    asm volatile("s_barrier" ::: "memory");
    asm volatile("s_waitcnt lgkmcnt(0)" ::: "memory");
    __builtin_amdgcn_sched_barrier(0);
    __builtin_amdgcn_s_setprio(1);
#pragma unroll
    for (int m = 0; m < 4; ++m)
#pragma unroll
      for (int n = 0; n < 2; ++n)
#pragma unroll
        for (int ks = 0; ks < 2; ++ks)
          acc[m][n] = MFMA_BF16(aLo[m][ks], bLo[n][ks], acc[m][n], 0, 0, 0);
    __builtin_amdgcn_s_setprio(0);
    if (st) { asm volatile("s_waitcnt vmcnt(6)" ::: "memory"); }
    else    { asm volatile("s_waitcnt vmcnt(2)" ::: "memory"); }  // A-h1 landed
    asm volatile("s_barrier" ::: "memory");

    // ---- phase 2: read A-h1 frags; stage next A-h1; MFMA (m4-7, n0-1)
#pragma unroll
    for (int m = 0; m < 4; ++m)
#pragma unroll
      for (int ks = 0; ks < 2; ++ks)
        aHi[m][ks] = *(const bf16x8*)(sb + 16384 + ((wr * 4 + m) * 2 + ks) * 512 + swz);
    if (st) {
#pragma unroll
      for (int g = 0; g < 2; ++g)
        gload_lds16(pA[g] + halfStep + k0n, db + 16384 + g * 4096 + wave * 512);
    }
    asm volatile("s_barrier" ::: "memory");
    asm volatile("s_waitcnt lgkmcnt(0)" ::: "memory");
    __builtin_amdgcn_sched_barrier(0);
    __builtin_amdgcn_s_setprio(1);
#pragma unroll
    for (int m = 0; m < 4; ++m)
#pragma unroll
      for (int n = 0; n < 2; ++n)
#pragma unroll
        for (int ks = 0; ks < 2; ++ks)
          acc[4 + m][n] = MFMA_BF16(aHi[m][ks], bLo[n][ks], acc[4 + m][n], 0, 0, 0);
    __builtin_amdgcn_s_setprio(0);
    if (st) { asm volatile("s_waitcnt vmcnt(6)" ::: "memory"); }
    else    { asm volatile("s_waitcnt vmcnt(0)" ::: "memory"); }  // B-h1 landed
    asm volatile("s_barrier" ::: "memory");

    // ---- phase 3: read B-h1 frags; stage next B-h1; MFMA (m0-3, n2-3)
#pragma unroll
    for (int n = 0; n < 2; ++n)
#pragma unroll
      for (int ks = 0; ks < 2; ++ks)
        bHi[n][ks] = *(const bf16x8*)(sb + 24576 + ((wc * 2 + n) * 2 + ks) * 512 + swz);
    if (st) {
#pragma unroll
      for (int g = 0; g < 2; ++g)
        gload_lds16(pB[g] + halfStep + k0n, db + 24576 + g * 4096 + wave * 512);
    }
    asm volatile("s_barrier" ::: "memory");
    asm volatile("s_waitcnt lgkmcnt(0)" ::: "memory");
    __builtin_amdgcn_sched_barrier(0);
    __builtin_amdgcn_s_setprio(1);
#pragma unroll
    for (int m = 0; m < 4; ++m)
#pragma unroll
      for (int n = 0; n < 2; ++n)
#pragma unroll
        for (int ks = 0; ks < 2; ++ks)
          acc[m][2 + n] = MFMA_BF16(aLo[m][ks], bHi[n][ks], acc[m][2 + n], 0, 0, 0);
    __builtin_amdgcn_s_setprio(0);
    if (st) { asm volatile("s_waitcnt vmcnt(6)" ::: "memory"); }  // next A-h0 landed
    asm volatile("s_barrier" ::: "memory");
  }

  // final leftover quadrant of the last tile
#pragma unroll
  for (int m = 0; m < 4; ++m)
#pragma unroll
    for (int n = 0; n < 2; ++n)
#pragma unroll
      for (int ks = 0; ks < 2; ++ks)
        acc[4 + m][2 + n] = MFMA_BF16(aHi[m][ks], bHi[n][ks], acc[4 + m][2 + n], 0, 0, 0);

  // epilogue: D layout col=lane&15, row=(lane>>4)*4+r
#pragma unroll
  for (int i = 0; i < 8; ++i) {
    const int grow0 = bm * 256 + (i >> 2) * 128 + wr * 64 + (i & 3) * 16 + hi * 4;
#pragma unroll
    for (int j = 0; j < 4; ++j) {
      const int gcol = bn * 256 + (j >> 1) * 128 + wc * 32 + (j & 1) * 16 + lo;
#pragma unroll
      for (int r = 0; r < 4; ++r)
        C[(size_t)(grow0 + r) * N + gcol] = f2bf(acc[i][j][r]);
    }
  }
}

// ---------------------------------------------------------------------------
// 3b) 128^2 2-phase GEMM for the small projections (M=512).
// ---------------------------------------------------------------------------
template <typename CT>
__global__ __launch_bounds__(256) void gemm_tn(
    const unsigned short* __restrict__ A,
    const unsigned short* __restrict__ Bt,
    CT* __restrict__ C, int M, int N, int K)
{
  __shared__ __align__(16) unsigned short sA[2][128 * 32];
  __shared__ __align__(16) unsigned short sB[2][128 * 32];
  const int tid  = threadIdx.x;
  const int wave = tid >> 6, lane = tid & 63;
  const int bm = blockIdx.y, bn = blockIdx.x;
  const int wr = wave >> 1, wc = wave & 1;
  const int lo = lane & 15, hi = lane >> 4;
  const int srow = lane >> 2, squad = lane & 3;

  const unsigned short* gA = A  + (size_t)(bm * 128 + srow) * K + squad * 8;
  const unsigned short* gB = Bt + (size_t)(bn * 128 + srow) * K + squad * 8;

  f32x4 acc[4][4];
#pragma unroll
  for (int i = 0; i < 4; ++i)
#pragma unroll
    for (int j = 0; j < 4; ++j) acc[i][j] = (f32x4){0.f, 0.f, 0.f, 0.f};

  const int kt = K >> 5;
#pragma unroll
  for (int c = 0; c < 2; ++c) {
    const int chunk = wave * 2 + c;
    gload_lds16(gA + (size_t)chunk * 16 * K, &sA[0][chunk * 512]);
    gload_lds16(gB + (size_t)chunk * 16 * K, &sB[0][chunk * 512]);
  }
  __syncthreads();

  int buf = 0;
  for (int t = 0; t < kt; ++t) {
    if (t + 1 < kt) {
      const int k0 = (t + 1) << 5;
#pragma unroll
      for (int c = 0; c < 2; ++c) {
        const int chunk = wave * 2 + c;
        gload_lds16(gA + (size_t)chunk * 16 * K + k0, &sA[buf ^ 1][chunk * 512]);
        gload_lds16(gB + (size_t)chunk * 16 * K + k0, &sB[buf ^ 1][chunk * 512]);
      }
    }
    bf16x8 af[4], bfr[4];
#pragma unroll
    for (int i = 0; i < 4; ++i) {
      af[i]  = *(const bf16x8*)&sA[buf][(wr * 64 + i * 16 + lo) * 32 + hi * 8];
      bfr[i] = *(const bf16x8*)&sB[buf][(wc * 64 + i * 16 + lo) * 32 + hi * 8];
    }
#pragma unroll
    for (int i = 0; i < 4; ++i)
#pragma unroll
      for (int j = 0; j < 4; ++j)
        acc[i][j] = MFMA_BF16(af[i], bfr[j], acc[i][j], 0, 0, 0);
    __syncthreads();
    buf ^= 1;
  }

#pragma unroll
  for (int i = 0; i < 4; ++i) {
    const int row0 = bm * 128 + wr * 64 + i * 16 + hi * 4;
#pragma unroll
    for (int j = 0; j < 4; ++j) {
      const int col = bn * 128 + wc * 64 + j * 16 + lo;
#pragma unroll
      for (int r = 0; r < 4; ++r) {
        const size_t idx = (size_t)(row0 + r) * N + col;
        if constexpr (sizeof(CT) == 2) C[idx] = (CT)f2bf(acc[i][j][r]);
        else                            C[idx] = acc[i][j][r];
      }
    }
  }
}

// ---------------------------------------------------------------------------
// 5) Flash attention, 4-way f-split: 512 WGs, bhs = (b*16+h)*4 + s.
// s-chunk processes tiles [s*65/4, (s+1)*65/4).  Writes UNNORMALIZED partials:
// pacc[bhs][d][q] f32, pml[bhs][{m,l}][q].  K/V prefetched one tile ahead.
// ---------------------------------------------------------------------------
__global__ __launch_bounds__(256) void attn_kernel(
    const unsigned short* __restrict__ qws,      // (512,1024) bf16, pre-scaled
    const unsigned short* __restrict__ KV,       // (33280,2048) bf16
    float* __restrict__ pacc, float* __restrict__ pml)
{
  const int bhs = blockIdx.x;                    // 0..511
  const int s = bhs & 3, h = (bhs >> 2) & 15, b = bhs >> 6;
  const int t0 = (s * 65) >> 2;
  const int t1 = ((s + 1) * 65) >> 2;
  const int tid = threadIdx.x;
  const int wave = tid >> 6, lane = tid & 63;
  const int lo = lane & 15, hi = lane >> 4;

  __shared__ __align__(16) unsigned short sK [64][72];
  __shared__ __align__(16) unsigned short sVT[64][72];
  __shared__ __align__(16) unsigned short sP [4][16][72];

  bf16x8 qf[2];
  {
    const unsigned short* p = qws + (size_t)(b * 64 + wave * 16 + lo) * 1024 + h * 64 + hi * 8;
    qf[0] = *(const bf16x8*)p;
    qf[1] = *(const bf16x8*)(p + 32);
  }
  float m[4] = {-1e30f, -1e30f, -1e30f, -1e30f};
  float l[4] = {0.f, 0.f, 0.f, 0.f};
  f32x4 acc[4];
#pragma unroll
  for (int i = 0; i < 4; ++i) acc[i] = (f32x4){0.f, 0.f, 0.f, 0.f};

  const int frow = tid >> 2, c4 = tid & 3;

  // prefetch tile t0 into registers
  bf16x8 kreg[2], vreg[2];
  {
    const size_t rb = (size_t)(b * 4160 + t0 * 64 + frow) * 2048 + h * 64;
#pragma unroll
    for (int rr = 0; rr < 2; ++rr) {
      const int d0 = rr * 32 + c4 * 8;
      kreg[rr] = *(const bf16x8*)(KV + rb + d0);
      vreg[rr] = *(const bf16x8*)(KV + rb + 1024 + d0);
    }
  }

  for (int t = t0; t < t1; ++t) {
    __syncthreads();   // prev tile's LDS reads done before overwrite
#pragma unroll
    for (int rr = 0; rr < 2; ++rr) {
      const int d0 = rr * 32 + c4 * 8;
      *(bf16x8*)&sK[frow][d0] = kreg[rr];
#pragma unroll
      for (int j = 0; j < 8; ++j) sVT[d0 + j][frow] = (unsigned short)vreg[rr][j];
    }
    __syncthreads();
    if (t + 1 < t1) {   // prefetch next tile; overlaps QK/softmax/PV below
      const size_t rb = (size_t)(b * 4160 + (t + 1) * 64 + frow) * 2048 + h * 64;
#pragma unroll
      for (int rr = 0; rr < 2; ++rr) {
        const int d0 = rr * 32 + c4 * 8;
        kreg[rr] = *(const bf16x8*)(KV + rb + d0);
        vreg[rr] = *(const bf16x8*)(KV + rb + 1024 + d0);
      }
    }

    // QK^T: A=Q (rows q=hi*4+r), B=K^T (cols f=nf*16+lo)
    f32x4 sim[4];
#pragma unroll
    for (int nf = 0; nf < 4; ++nf) {
      f32x4 a0 = (f32x4){0.f, 0.f, 0.f, 0.f};
#pragma unroll
      for (int ks = 0; ks < 2; ++ks) {
        bf16x8 kf = *(const bf16x8*)&sK[nf * 16 + lo][ks * 32 + hi * 8];
        a0 = MFMA_BF16(qf[ks], kf, a0, 0, 0, 0);
      }
      sim[nf] = a0;
    }

    // online softmax (row stats across the 16 low lanes)
    float pr[4][4];
    float corr[4];
#pragma unroll
    for (int r = 0; r < 4; ++r) {
      float tm = fmaxf(fmaxf(sim[0][r], sim[1][r]), fmaxf(sim[2][r], sim[3][r]));
#pragma unroll
      for (int sh = 1; sh < 16; sh <<= 1) tm = fmaxf(tm, __shfl_xor(tm, sh, 64));
      const float mn = fmaxf(m[r], tm);
      corr[r] = __expf(m[r] - mn);
      float rs = 0.f;
#pragma unroll
      for (int nf = 0; nf < 4; ++nf) {
        float p = __expf(sim[nf][r] - mn);
        pr[r][nf] = p;
        rs += p;
      }
#pragma unroll
      for (int sh = 1; sh < 16; sh <<= 1) rs += __shfl_xor(rs, sh, 64);
      l[r] = l[r] * corr[r] + rs;
      m[r] = mn;
    }

    // redistribute corr from (hi,r) layout to col-q (=lo) layout
    {
      const int r2 = lane & 3;
      float csel = r2 == 0 ? corr[0] : r2 == 1 ? corr[1] : r2 == 2 ? corr[2] : corr[3];
      const int src = ((lane & 15) >> 2) * 16 + (lane & 3);
      const float cacc = __shfl(csel, src, 64);
#pragma unroll
      for (int i = 0; i < 4; ++i) acc[i] *= cacc;
    }

    // P -> sP (wave-private; within-wave RAW ordered by lgkmcnt)
#pragma unroll
    for (int r = 0; r < 4; ++r)
#pragma unroll
      for (int nf = 0; nf < 4; ++nf)
        sP[wave][hi * 4 + r][nf * 16 + lo] = f2bf(pr[r][nf]);

    // PV: out^T = V^T @ P^T  (A rows = vd, B cols = q)
#pragma unroll
    for (int ks = 0; ks < 2; ++ks) {
      bf16x8 pf = *(const bf16x8*)&sP[wave][lo][ks * 32 + hi * 8];
#pragma unroll
      for (int i = 0; i < 4; ++i) {
        bf16x8 vf = *(const bf16x8*)&sVT[i * 16 + lo][ks * 32 + hi * 8];
        acc[i] = MFMA_BF16(vf, pf, acc[i], 0, 0, 0);
      }
    }
  }

  // write partials: pml[bhs][{m,l}][q], pacc[bhs][d][q] (coalesced in q=lo)
  if (lo == 0) {
#pragma unroll
    for (int r = 0; r < 4; ++r) {
      pml[bhs * 128 + wave * 16 + hi * 4 + r]      = m[r];
      pml[bhs * 128 + 64 + wave * 16 + hi * 4 + r] = l[r];
    }
  }
#pragma unroll
  for (int i = 0; i < 4; ++i)
#pragma unroll
    for (int r = 0; r < 4; ++r)
      pacc[bhs * 4096 + (i * 16 + hi * 4 + r) * 64 + wave * 16 + lo] = acc[i][r];
}

// ---------------------------------------------------------------------------
// 5b) Combine 4 f-split partials -> attn_out bf16.  128 blocks (one per bh).
// ---------------------------------------------------------------------------
__global__ __launch_bounds__(256) void attn_combine(
    const float* __restrict__ pacc, const float* __restrict__ pml,
    unsigned short* __restrict__ attn_out)
{
  const int bh = blockIdx.x;
  const int b = bh >> 4, h = bh & 15;
  const int t = threadIdx.x;
  const int q = t & 63, dg = t >> 6;
  const int base = bh << 2;

  float mm[4], ll[4];
#pragma unroll
  for (int s = 0; s < 4; ++s) {
    mm[s] = pml[(base + s) * 128 + q];
    ll[s] = pml[(base + s) * 128 + 64 + q];
  }
  float M = fmaxf(fmaxf(mm[0], mm[1]), fmaxf(mm[2], mm[3]));
  float e[4];
  float L = 0.f;
#pragma unroll
  for (int s = 0; s < 4; ++s) { e[s] = __expf(mm[s] - M); L += e[s] * ll[s]; }
  const float inv = 1.0f / L;

#pragma unroll
  for (int dd = 0; dd < 16; ++dd) {
    const int d = dg * 16 + dd;
    float v = 0.f;
#pragma unroll
    for (int s = 0; s < 4; ++s)
      v += e[s] * pacc[(base + s) * 4096 + d * 64 + q];
    attn_out[(size_t)(b * 64 + q) * 1024 + h * 64 + d] = f2bf(v * inv);
  }
}

// ---------------------------------------------------------------------------
extern "C" void kernel_launch(void* const* d_in, const int* in_sizes, int n_in,
                              void* d_out, int out_size, void* d_ws, size_t ws_size,
                              hipStream_t stream) {
  const float* features = (const float*)d_in[0];
  const float* latents  = (const float*)d_in[1];
  const float* lnm_w = (const float*)d_in[2];
  const float* lnm_b = (const float*)d_in[3];
  const float* lnl_w = (const float*)d_in[4];
  const float* lnl_b = (const float*)d_in[5];
  const float* Wq = (const float*)d_in[6];
  const float* Wk = (const float*)d_in[7];
  const float* Wv = (const float*)d_in[8];
  const float* Wo = (const float*)d_in[9];
  float* out = (float*)d_out;

  char* ws = (char*)d_ws;
  unsigned short* kv_ln    = (unsigned short*)(ws);               // 68,157,440
  unsigned short* Wkv_t    = (unsigned short*)(ws + 68157440);    //  4,194,304
  unsigned short* Wq_t     = (unsigned short*)(ws + 72351744);    //  2,097,152
  unsigned short* Wo_t     = (unsigned short*)(ws + 74448896);    //  2,097,152
  unsigned short* lat_ln   = (unsigned short*)(ws + 76546048);    //  1,048,576
  unsigned short* q_ws     = (unsigned short*)(ws + 77594624);    //  1,048,576
  unsigned short* attn_out = (unsigned short*)(ws + 78643200);    //  1,048,576
  unsigned short* KV       = (unsigned short*)(ws + 79691776);    // 136,314,880
  // attn partials overlay the kv_ln region (dead after the KV GEMM):
  float* pacc = (float*)(ws);                                     //  8,388,608
  float* pml  = (float*)(ws + 8388608);                           //    262,144

  ln_kernel<<<33280, 256, 0, stream>>>(features, latents, lnm_w, lnm_b, lnl_w, lnl_b,
                                       kv_ln, lat_ln);
  wcast_kernel<<<dim3(32, 128), 256, 0, stream>>>(Wq, Wk, Wv, Wo, Wkv_t, Wq_t, Wo_t);
  gemm256_bf16<<<dim3(8, 130), 512, 0, stream>>>(kv_ln, Wkv_t, KV, 33280, 2048, 1024);
  gemm_tn<unsigned short><<<dim3(8, 4), 256, 0, stream>>>(lat_ln, Wq_t, q_ws, 512, 1024, 1024);
  attn_kernel<<<512, 256, 0, stream>>>(q_ws, KV, pacc, pml);
  attn_combine<<<128, 256, 0, stream>>>(pacc, pml, attn_out);
  gemm_tn<float><<<dim3(8, 4), 256, 0, stream>>>(attn_out, Wo_t, out, 512, 1024, 1024);
}